// Round 1
// baseline (41668.399 us; speedup 1.0000x reference)
//
#include <hip/hip_runtime.h>
#include <cstdint>

#define HID 200
#define HALF 100
#define N_EDUS 32768
#define N_STEPS (2*N_EDUS - 1)   // 65535
#define KMAX 32766               // chain computes M_1..M_32766 (M_0 = enc[0])

// ---------------- generic tiled GEMM: C[m][n] = bias[n] + sum_k A[m][k]*B[n][k] ----------------
// A: [M x K] row-stride lda ; B: [N x K] row-stride ldb (i.e. C = A @ B^T)
__global__ __launch_bounds__(256) void gemm_bt(const float* __restrict__ A, int lda,
    const float* __restrict__ B, int ldb, const float* __restrict__ bias,
    float* __restrict__ C, int ldc, int M, int N, int K)
{
    __shared__ float As[32][68];   // [kk][mm], pad 68 keeps float4 rows 16B-aligned
    __shared__ float Bs[32][68];
    const int tid = threadIdx.x;
    const int tx = tid & 15, ty = tid >> 4;
    const int m0 = blockIdx.x * 64, n0 = blockIdx.y * 64;
    float acc[4][4] = {};
    for (int kc = 0; kc < K; kc += 32) {
        const int kk = tid & 31, r0 = tid >> 5;
        #pragma unroll
        for (int p = 0; p < 8; ++p) {
            const int mm = r0 + p * 8;
            const int m = m0 + mm, n = n0 + mm, kg = kc + kk;
            As[kk][mm] = (m < M && kg < K) ? A[(size_t)m * lda + kg] : 0.f;
            Bs[kk][mm] = (n < N && kg < K) ? B[(size_t)n * ldb + kg] : 0.f;
        }
        __syncthreads();
        #pragma unroll
        for (int kk2 = 0; kk2 < 32; ++kk2) {
            const float4 a = *(const float4*)&As[kk2][tx * 4];
            const float4 b = *(const float4*)&Bs[kk2][ty * 4];
            const float av[4] = {a.x, a.y, a.z, a.w};
            const float bv[4] = {b.x, b.y, b.z, b.w};
            #pragma unroll
            for (int r = 0; r < 4; ++r)
                #pragma unroll
                for (int c = 0; c < 4; ++c)
                    acc[r][c] += av[r] * bv[c];
        }
        __syncthreads();
    }
    #pragma unroll
    for (int r = 0; r < 4; ++r) {
        const int m = m0 + tx * 4 + r;
        if (m >= M) continue;
        #pragma unroll
        for (int c = 0; c < 4; ++c) {
            const int n = n0 + ty * 4 + c;
            if (n < N) C[(size_t)m * ldc + n] = acc[r][c] + (bias ? bias[n] : 0.f);
        }
    }
}

// ---------------- prep: build stacked weight mats + missing-node projections, zero out ----------------
// WAB[48][200]: rows 0..23 = Wcat[:,0:200] (A), rows 24..47 = Wcat[:,200:400] (B)
// WBC[48][200]: rows 0..23 = B, rows 24..47 = Wcat[:,400:600] (C)
// Wcat rows: [W_act(2); W_lab(19); W_dir(3)]
__global__ void prep_kernel(const float* __restrict__ W_act, const float* __restrict__ W_lab,
    const float* __restrict__ W_dir, const float* __restrict__ miss,
    float* __restrict__ WAB, float* __restrict__ WBC,
    float* __restrict__ msAB, float* __restrict__ msBC, float* __restrict__ out)
{
    const int tid = threadIdx.x;
    if (tid == 0) out[0] = 0.f;
    for (int i = tid; i < 48 * 200; i += 256) {
        const int r = i / 200, c = i % 200;
        const int rr = r % 24;
        const float* src = (rr < 2) ? (W_act + rr * 600)
                         : (rr < 21) ? (W_lab + (rr - 2) * 600)
                                     : (W_dir + (rr - 21) * 600);
        WAB[i] = src[c + (r < 24 ? 0 : 200)];
        WBC[i] = src[c + (r < 24 ? 200 : 400)];
    }
    __syncthreads();
    if (tid < 48) {
        float sA = 0.f, sB = 0.f;
        for (int c = 0; c < 200; ++c) {
            sA += WAB[tid * 200 + c] * miss[c];
            sB += WBC[tid * 200 + c] * miss[c];
        }
        msAB[tid] = sA;
        msBC[tid] = sB;
    }
}

// ---------------- sequential treelstm chain ----------------
__device__ __forceinline__ float sigf(float x) {
    x = fminf(fmaxf(x, -30.f), 30.f);
    return 1.f / (1.f + __expf(-x));
}
__device__ __forceinline__ float tanhf_(float x) {
    const float e = __expf(-2.f * fabsf(x));
    const float r = (1.f - e) / (1.f + e);
    return x < 0.f ? -r : r;
}

// 512 threads: T -> (d = T>>2 in [0,128), q = T&3). Active d<100.
// lane (d,q): holds W1 rows {d, d+100, d+200, d+300, d+400} over i-chunk [25q,25q+25) in 125 VGPRs.
// h exchanged via LDS (stride-36 chunk layout, double-buffered); c[d] persistent in q==0 lane's register.
// P row (enc-half of gates, incl. b_tree) and c2 = enc[k][100+d] register-prefetched one step ahead.
__global__ __launch_bounds__(512) void chain_kernel(const float* __restrict__ enc,
    const float* __restrict__ W_tree, const float* __restrict__ P, float* __restrict__ M)
{
    const int T = threadIdx.x;
    const int d = T >> 2, q = T & 3;
    const bool act = (d < 100);
    const bool g0 = act && (q == 0);
    __shared__ float hbuf[2][4 * 36];

    if (T < 200) M[T] = enc[T];   // M_0 = enc[0]

    float W[5][25];
    if (act) {
        #pragma unroll
        for (int g = 0; g < 5; ++g)
            #pragma unroll
            for (int j = 0; j < 25; ++j)
                W[g][j] = W_tree[(size_t)(g * 100 + d) * 200 + q * 25 + j];
    }
    const int hslot = (d / 25) * 36 + (d % 25);
    float c_reg = 0.f, pc[5] = {}, c2c = 0.f;
    if (g0) {
        c_reg = enc[100 + d];
        hbuf[0][hslot] = enc[d];
        #pragma unroll
        for (int g = 0; g < 5; ++g) pc[g] = P[(size_t)1 * 512 + g * 100 + d];
        c2c = enc[(size_t)1 * 200 + 100 + d];
    }
    __syncthreads();

    int cur = 0;
    for (int k = 1; k <= KMAX; ++k) {
        // prefetch next step's P row + c2 (consumed after this step's full latency)
        float pn[5] = {}, c2n = 0.f;
        if (g0 && k < KMAX) {
            #pragma unroll
            for (int g = 0; g < 5; ++g) pn[g] = P[(size_t)(k + 1) * 512 + g * 100 + d];
            c2n = enc[(size_t)(k + 1) * 200 + 100 + d];
        }
        float part[5] = {0.f, 0.f, 0.f, 0.f, 0.f};
        if (act) {
            float hr[25];
            const float* hb = &hbuf[cur][q * 36];
            #pragma unroll
            for (int jj = 0; jj < 6; ++jj) {
                const float4 h4 = *(const float4*)(hb + jj * 4);
                hr[jj * 4 + 0] = h4.x; hr[jj * 4 + 1] = h4.y;
                hr[jj * 4 + 2] = h4.z; hr[jj * 4 + 3] = h4.w;
            }
            hr[24] = hb[24];
            #pragma unroll
            for (int g = 0; g < 5; ++g) {
                float a = 0.f;
                #pragma unroll
                for (int j = 0; j < 25; ++j) a = fmaf(W[g][j], hr[j], a);
                part[g] = a;
            }
        }
        #pragma unroll
        for (int g = 0; g < 5; ++g) {   // quad butterfly reduce (partners within quad)
            part[g] += __shfl_xor(part[g], 1, 64);
            part[g] += __shfl_xor(part[g], 2, 64);
        }
        if (g0) {
            const float gi  = part[0] + pc[0];
            const float gf1 = part[1] + pc[1];
            const float gf2 = part[2] + pc[2];
            const float go  = part[3] + pc[3];
            const float gu  = part[4] + pc[4];
            const float cn = sigf(gi) * tanhf_(gu) + sigf(gf1) * c_reg + sigf(gf2) * c2c;
            const float hn = sigf(go) * tanhf_(cn);
            c_reg = cn;
            hbuf[cur ^ 1][hslot] = hn;
            float* Mr = M + (size_t)k * 200;
            Mr[d] = hn;
            Mr[100 + d] = cn;
            if (k < KMAX) {
                #pragma unroll
                for (int g = 0; g < 5; ++g) pc[g] = pn[g];
                c2c = c2n;
            }
        }
        cur ^= 1;
        __syncthreads();
    }
}

// ---------------- per-step CE losses + reduction ----------------
// TM[k][0:24] = A@M_k, TM[k][24:48] = B@M_k ; TE[i][0:24] = B@enc[i], TE[i][24:48] = C@enc[i]
__global__ __launch_bounds__(256) void loss_kernel(const float* __restrict__ TM,
    const float* __restrict__ TE, const float* __restrict__ msAB, const float* __restrict__ msBC,
    const float* __restrict__ b_act, const float* __restrict__ b_lab, const float* __restrict__ b_dir,
    const int* __restrict__ ga, const int* __restrict__ gl, const int* __restrict__ gd,
    float* __restrict__ out)
{
    const int t = blockIdx.x * 256 + threadIdx.x;
    float loss = 0.f;
    if (t < N_STEPS) {
        const float *v1, *v0, *vb;
        if (t == 0)      { v1 = msAB; v0 = msAB + 24; vb = TE + 24; }
        else if (t == 1) { v1 = msAB; v0 = TE;        vb = TE + 48 + 24; }
        else if ((t & 1) == 0) {
            const int k = t >> 1;                     // k in [1, 32767]
            v1 = TM + (size_t)(k - 1) * 48;
            v0 = TE + (size_t)k * 48;
            vb = (k < N_EDUS - 1) ? (TE + (size_t)(k + 1) * 48 + 24) : (msBC + 24);
        } else {
            const int k = t >> 1;                     // k in [1, 32766]
            v1 = msAB;
            v0 = TM + (size_t)k * 48 + 24;
            vb = TE + (size_t)(k + 1) * 48 + 24;
        }
        float l[24];
        #pragma unroll
        for (int j = 0; j < 24; ++j) l[j] = v1[j] + v0[j] + vb[j];
        l[0] += b_act[0]; l[1] += b_act[1];
        #pragma unroll
        for (int j = 0; j < 19; ++j) l[2 + j] += b_lab[j];
        #pragma unroll
        for (int j = 0; j < 3; ++j) l[21 + j] += b_dir[j];
        const int ya = ga[t], yl = gl[t], yd = gd[t];
        {   // action (2)
            const float m = fmaxf(l[0], l[1]);
            const float s = __expf(l[0] - m) + __expf(l[1] - m);
            loss += m + __logf(s) - (ya == 0 ? l[0] : l[1]);
        }
        {   // label (19)
            float m = l[2];
            #pragma unroll
            for (int j = 1; j < 19; ++j) m = fmaxf(m, l[2 + j]);
            float s = 0.f, ly = 0.f;
            #pragma unroll
            for (int j = 0; j < 19; ++j) {
                s += __expf(l[2 + j] - m);
                if (j == yl) ly = l[2 + j];
            }
            loss += m + __logf(s) - ly;
        }
        {   // direction (3)
            const float m = fmaxf(fmaxf(l[21], l[22]), l[23]);
            const float s = __expf(l[21] - m) + __expf(l[22] - m) + __expf(l[23] - m);
            const float ly = (yd == 0) ? l[21] : (yd == 1 ? l[22] : l[23]);
            loss += m + __logf(s) - ly;
        }
    }
    #pragma unroll
    for (int off = 32; off > 0; off >>= 1) loss += __shfl_down(loss, off, 64);
    __shared__ float wsum[4];
    const int lane = threadIdx.x & 63, wv = threadIdx.x >> 6;
    if (lane == 0) wsum[wv] = loss;
    __syncthreads();
    if (threadIdx.x == 0) atomicAdd(out, wsum[0] + wsum[1] + wsum[2] + wsum[3]);
}

// ---------------- launch ----------------
extern "C" void kernel_launch(void* const* d_in, const int* in_sizes, int n_in,
                              void* d_out, int out_size, void* d_ws, size_t ws_size,
                              hipStream_t stream) {
    const float* enc_cls = (const float*)d_in[0];
    const float* W_proj  = (const float*)d_in[1];
    const float* b_proj  = (const float*)d_in[2];
    const float* miss    = (const float*)d_in[3];
    const float* W_act   = (const float*)d_in[4];
    const float* b_act   = (const float*)d_in[5];
    const float* W_lab   = (const float*)d_in[6];
    const float* b_lab   = (const float*)d_in[7];
    const float* W_dir   = (const float*)d_in[8];
    const float* b_dir   = (const float*)d_in[9];
    const float* W_tree  = (const float*)d_in[10];
    const float* b_tree  = (const float*)d_in[11];
    const int*   ga      = (const int*)d_in[12];
    const int*   gl      = (const int*)d_in[13];
    const int*   gd      = (const int*)d_in[14];
    float* out = (float*)d_out;

    // workspace layout (floats)
    float* ws   = (float*)d_ws;
    float* enc  = ws;                         // 32768*200      = 6,553,600
    float* Mar  = ws + 6553600;               // 32767*200      = 6,553,400
    float* P    = ws + 13107000;              // 32767*512      = 16,776,704 (row 0 unused)
    float* WAB  = ws + 29883704;              // 48*200
    float* WBC  = WAB + 9600;                 // 48*200
    float* msAB = WBC + 9600;                 // 48
    float* msBC = msAB + 48;                  // 48
    // loss tables overlay P's region (P is dead after chain_kernel)
    float* TM = P;                            // 32767*48
    float* TE = P + 1572816;                  // 32768*48

    // 1) enc = enc_cls @ W_proj^T + b_proj
    gemm_bt<<<dim3(512, 4, 1), 256, 0, stream>>>(enc_cls, 768, W_proj, 768, b_proj,
                                                 enc, 200, N_EDUS, 200, 768);
    // 2) P[k] = W_tree[:,100:200] @ enc_h[k] + b_tree, for k = 1..32766
    gemm_bt<<<dim3(512, 8, 1), 256, 0, stream>>>(enc + 200, 200, W_tree + 100, 200, b_tree,
                                                 P + 512, 512, KMAX, 500, 100);
    // 3) stacked loss-weight matrices + missing projections + zero out
    prep_kernel<<<1, 256, 0, stream>>>(W_act, W_lab, W_dir, miss, WAB, WBC, msAB, msBC, out);
    // 4) sequential treelstm chain (single workgroup)
    chain_kernel<<<1, 512, 0, stream>>>(enc, W_tree, P, Mar);
    // 5) TM = M @ [A;B]^T   (overlays P)
    gemm_bt<<<dim3(512, 1, 1), 256, 0, stream>>>(Mar, 200, WAB, 200, nullptr,
                                                 TM, 48, KMAX + 1, 48, 200);
    // 6) TE = enc @ [B;C]^T
    gemm_bt<<<dim3(512, 1, 1), 256, 0, stream>>>(enc, 200, WBC, 200, nullptr,
                                                 TE, 48, N_EDUS, 48, 200);
    // 7) per-step CE + global sum
    loss_kernel<<<dim3(256, 1, 1), 256, 0, stream>>>(TM, TE, msAB, msBC,
                                                     b_act, b_lab, b_dir, ga, gl, gd, out);
}

// Round 2
// 36240.234 us; speedup vs baseline: 1.1498x; 1.1498x over previous
//
#include <hip/hip_runtime.h>
#include <cstdint>

#define HID 200
#define HALF 100
#define N_EDUS 32768
#define N_STEPS (2*N_EDUS - 1)   // 65535
#define KMAX 32766               // chain computes M_1..M_32766 (M_0 = enc[0])

// ---------------- generic tiled GEMM: C[m][n] = bias[n] + sum_k A[m][k]*B[n][k] ----------------
__global__ __launch_bounds__(256) void gemm_bt(const float* __restrict__ A, int lda,
    const float* __restrict__ B, int ldb, const float* __restrict__ bias,
    float* __restrict__ C, int ldc, int M, int N, int K)
{
    __shared__ float As[32][68];
    __shared__ float Bs[32][68];
    const int tid = threadIdx.x;
    const int tx = tid & 15, ty = tid >> 4;
    const int m0 = blockIdx.x * 64, n0 = blockIdx.y * 64;
    float acc[4][4] = {};
    for (int kc = 0; kc < K; kc += 32) {
        const int kk = tid & 31, r0 = tid >> 5;
        #pragma unroll
        for (int p = 0; p < 8; ++p) {
            const int mm = r0 + p * 8;
            const int m = m0 + mm, n = n0 + mm, kg = kc + kk;
            As[kk][mm] = (m < M && kg < K) ? A[(size_t)m * lda + kg] : 0.f;
            Bs[kk][mm] = (n < N && kg < K) ? B[(size_t)n * ldb + kg] : 0.f;
        }
        __syncthreads();
        #pragma unroll
        for (int kk2 = 0; kk2 < 32; ++kk2) {
            const float4 a = *(const float4*)&As[kk2][tx * 4];
            const float4 b = *(const float4*)&Bs[kk2][ty * 4];
            const float av[4] = {a.x, a.y, a.z, a.w};
            const float bv[4] = {b.x, b.y, b.z, b.w};
            #pragma unroll
            for (int r = 0; r < 4; ++r)
                #pragma unroll
                for (int c = 0; c < 4; ++c)
                    acc[r][c] += av[r] * bv[c];
        }
        __syncthreads();
    }
    #pragma unroll
    for (int r = 0; r < 4; ++r) {
        const int m = m0 + tx * 4 + r;
        if (m >= M) continue;
        #pragma unroll
        for (int c = 0; c < 4; ++c) {
            const int n = n0 + ty * 4 + c;
            if (n < N) C[(size_t)m * ldc + n] = acc[r][c] + (bias ? bias[n] : 0.f);
        }
    }
}

// ---------------- prep ----------------
__global__ void prep_kernel(const float* __restrict__ W_act, const float* __restrict__ W_lab,
    const float* __restrict__ W_dir, const float* __restrict__ miss,
    float* __restrict__ WAB, float* __restrict__ WBC,
    float* __restrict__ msAB, float* __restrict__ msBC, float* __restrict__ out)
{
    const int tid = threadIdx.x;
    if (tid == 0) out[0] = 0.f;
    for (int i = tid; i < 48 * 200; i += 256) {
        const int r = i / 200, c = i % 200;
        const int rr = r % 24;
        const float* src = (rr < 2) ? (W_act + rr * 600)
                         : (rr < 21) ? (W_lab + (rr - 2) * 600)
                                     : (W_dir + (rr - 21) * 600);
        WAB[i] = src[c + (r < 24 ? 0 : 200)];
        WBC[i] = src[c + (r < 24 ? 200 : 400)];
    }
    __syncthreads();
    if (tid < 48) {
        float sA = 0.f, sB = 0.f;
        for (int c = 0; c < 200; ++c) {
            sA += WAB[tid * 200 + c] * miss[c];
            sB += WBC[tid * 200 + c] * miss[c];
        }
        msAB[tid] = sA;
        msBC[tid] = sB;
    }
}

// ---------------- sequential treelstm chain ----------------
__device__ __forceinline__ float sigf(float x) {
    // 1/(1+e^-x); exp overflow -> rcp(inf)=0, correct limit
    return __builtin_amdgcn_rcpf(1.f + __expf(-x));
}
__device__ __forceinline__ float tanhf_(float x) {
    // tanh(x) = 1 - 2/(1+e^{2x}); overflow-safe at both ends
    return 1.f - 2.f * __builtin_amdgcn_rcpf(1.f + __expf(2.f * x));
}

// raw barrier: drain LDS only, leave global prefetch loads (vmcnt) in flight
#define BAR() asm volatile("s_waitcnt lgkmcnt(0)\n\ts_barrier" ::: "memory")

// 512 threads: T -> (d = T>>2 in [0,128), q = T&3). Active d<100.
// lane (d,q): W_tree[:,0:100] rows {d,d+100,..,d+400} over j-chunk [25q,25q+25) in 125 VGPRs.
// gate epilogue distributed over quad: q0=sig(i)*tanh(u), q1=sig(f1)*c1, q2=sig(f2)*c2, q3=sig(o).
// P row (enc-half of gates incl. b_tree) + c2 prefetched 2 steps ahead, per-quad-lane.
__global__ __launch_bounds__(512, 2) void chain_kernel(const float* __restrict__ enc,
    const float* __restrict__ W_tree, const float* __restrict__ P, float* __restrict__ M)
{
    const int T = threadIdx.x;
    const int d = T >> 2, q = T & 3;
    const bool act = (d < 100);
    __shared__ float hbuf[2][4 * 36];

    if (T < 200) M[T] = enc[T];   // M_0 = enc[0]

    float W[5][25];
    if (act) {
        #pragma unroll
        for (int g = 0; g < 5; ++g)
            #pragma unroll
            for (int j = 0; j < 25; ++j)
                W[g][j] = W_tree[(size_t)(g * 100 + d) * 200 + q * 25 + j];
    }
    const int hslot = (d / 25) * 36 + (d % 25);
    const int goA = q * 100 + d;      // this lane's primary gate slot in a P row
    const int goB = 400 + d;          // u-gate slot (q0 only)

    float c_reg = 0.f;                                // cell state, lives at q1
    float pa_c = 0, pb_c = 0, c2_c = 0;               // step k
    float pa_1 = 0, pb_1 = 0, c2_1 = 0;               // step k+1
    if (act) {
        if (q == 1) c_reg = enc[100 + d];
        if (q == 0) hbuf[0][hslot] = enc[d];
        pa_c = P[(size_t)1 * 512 + goA];
        if (q == 0) pb_c = P[(size_t)1 * 512 + goB];
        if (q == 2) c2_c = enc[(size_t)1 * 200 + 100 + d];
        pa_1 = P[(size_t)2 * 512 + goA];
        if (q == 0) pb_1 = P[(size_t)2 * 512 + goB];
        if (q == 2) c2_1 = enc[(size_t)2 * 200 + 100 + d];
    }
    BAR();

    int cur = 0;
    for (int k = 1; k <= KMAX; ++k) {
        // prefetch step k+2 (2-step distance covers HBM latency across raw barriers)
        float pa_2 = 0.f, pb_2 = 0.f, c2_2 = 0.f;
        if (act && k + 2 <= KMAX) {
            pa_2 = P[(size_t)(k + 2) * 512 + goA];
            if (q == 0) pb_2 = P[(size_t)(k + 2) * 512 + goB];
            if (q == 2) c2_2 = enc[(size_t)(k + 2) * 200 + 100 + d];
        }
        float s[5] = {0.f, 0.f, 0.f, 0.f, 0.f};
        if (act) {
            float hr[25];
            const float* hb = &hbuf[cur][q * 36];
            #pragma unroll
            for (int jj = 0; jj < 6; ++jj) {
                const float4 h4 = *(const float4*)(hb + jj * 4);
                hr[jj * 4 + 0] = h4.x; hr[jj * 4 + 1] = h4.y;
                hr[jj * 4 + 2] = h4.z; hr[jj * 4 + 3] = h4.w;
            }
            hr[24] = hb[24];
            #pragma unroll
            for (int g = 0; g < 5; ++g) {
                float a = 0.f;
                #pragma unroll
                for (int j = 0; j < 25; ++j) a = fmaf(W[g][j], hr[j], a);
                s[g] = a;
            }
        }
        #pragma unroll
        for (int g = 0; g < 5; ++g) {   // quad butterfly: all 4 quad lanes get full sums
            s[g] += __shfl_xor(s[g], 1, 64);
            s[g] += __shfl_xor(s[g], 2, 64);
        }
        if (act) {
            // distributed gates
            const float prim = (q == 0) ? s[0] : (q == 1) ? s[1] : (q == 2) ? s[2] : s[3];
            const float sg = sigf(prim + pa_c);            // at q3 this is sig(o)
            const float mult = (q == 0) ? tanhf_(s[4] + pb_c)
                             : (q == 1) ? c_reg
                             : (q == 2) ? c2_c : 0.f;
            float a = sg * mult;
            a += __shfl_xor(a, 1, 64);
            a += __shfl_xor(a, 2, 64);                     // a == new cell c, all quad lanes
            if (q == 3) {
                const float h = sg * tanhf_(a);
                hbuf[cur ^ 1][hslot] = h;
                M[(size_t)k * 200 + d] = h;
            } else if (q == 1) {
                c_reg = a;
                M[(size_t)k * 200 + 100 + d] = a;
            }
            pa_c = pa_1; pb_c = pb_1; c2_c = c2_1;
            pa_1 = pa_2; pb_1 = pb_2; c2_1 = c2_2;
        }
        cur ^= 1;
        BAR();
    }
}

// ---------------- per-step CE losses + reduction ----------------
__global__ __launch_bounds__(256) void loss_kernel(const float* __restrict__ TM,
    const float* __restrict__ TE, const float* __restrict__ msAB, const float* __restrict__ msBC,
    const float* __restrict__ b_act, const float* __restrict__ b_lab, const float* __restrict__ b_dir,
    const int* __restrict__ ga, const int* __restrict__ gl, const int* __restrict__ gd,
    float* __restrict__ out)
{
    const int t = blockIdx.x * 256 + threadIdx.x;
    float loss = 0.f;
    if (t < N_STEPS) {
        const float *v1, *v0, *vb;
        if (t == 0)      { v1 = msAB; v0 = msAB + 24; vb = TE + 24; }
        else if (t == 1) { v1 = msAB; v0 = TE;        vb = TE + 48 + 24; }
        else if ((t & 1) == 0) {
            const int k = t >> 1;
            v1 = TM + (size_t)(k - 1) * 48;
            v0 = TE + (size_t)k * 48;
            vb = (k < N_EDUS - 1) ? (TE + (size_t)(k + 1) * 48 + 24) : (msBC + 24);
        } else {
            const int k = t >> 1;
            v1 = msAB;
            v0 = TM + (size_t)k * 48 + 24;
            vb = TE + (size_t)(k + 1) * 48 + 24;
        }
        float l[24];
        #pragma unroll
        for (int j = 0; j < 24; ++j) l[j] = v1[j] + v0[j] + vb[j];
        l[0] += b_act[0]; l[1] += b_act[1];
        #pragma unroll
        for (int j = 0; j < 19; ++j) l[2 + j] += b_lab[j];
        #pragma unroll
        for (int j = 0; j < 3; ++j) l[21 + j] += b_dir[j];
        const int ya = ga[t], yl = gl[t], yd = gd[t];
        {
            const float m = fmaxf(l[0], l[1]);
            const float sum = __expf(l[0] - m) + __expf(l[1] - m);
            loss += m + __logf(sum) - (ya == 0 ? l[0] : l[1]);
        }
        {
            float m = l[2];
            #pragma unroll
            for (int j = 1; j < 19; ++j) m = fmaxf(m, l[2 + j]);
            float sum = 0.f, ly = 0.f;
            #pragma unroll
            for (int j = 0; j < 19; ++j) {
                sum += __expf(l[2 + j] - m);
                if (j == yl) ly = l[2 + j];
            }
            loss += m + __logf(sum) - ly;
        }
        {
            const float m = fmaxf(fmaxf(l[21], l[22]), l[23]);
            const float sum = __expf(l[21] - m) + __expf(l[22] - m) + __expf(l[23] - m);
            const float ly = (yd == 0) ? l[21] : (yd == 1 ? l[22] : l[23]);
            loss += m + __logf(sum) - ly;
        }
    }
    #pragma unroll
    for (int off = 32; off > 0; off >>= 1) loss += __shfl_down(loss, off, 64);
    __shared__ float wsum[4];
    const int lane = threadIdx.x & 63, wv = threadIdx.x >> 6;
    if (lane == 0) wsum[wv] = loss;
    __syncthreads();
    if (threadIdx.x == 0) atomicAdd(out, wsum[0] + wsum[1] + wsum[2] + wsum[3]);
}

// ---------------- launch ----------------
extern "C" void kernel_launch(void* const* d_in, const int* in_sizes, int n_in,
                              void* d_out, int out_size, void* d_ws, size_t ws_size,
                              hipStream_t stream) {
    const float* enc_cls = (const float*)d_in[0];
    const float* W_proj  = (const float*)d_in[1];
    const float* b_proj  = (const float*)d_in[2];
    const float* miss    = (const float*)d_in[3];
    const float* W_act   = (const float*)d_in[4];
    const float* b_act   = (const float*)d_in[5];
    const float* W_lab   = (const float*)d_in[6];
    const float* b_lab   = (const float*)d_in[7];
    const float* W_dir   = (const float*)d_in[8];
    const float* b_dir   = (const float*)d_in[9];
    const float* W_tree  = (const float*)d_in[10];
    const float* b_tree  = (const float*)d_in[11];
    const int*   ga      = (const int*)d_in[12];
    const int*   gl      = (const int*)d_in[13];
    const int*   gd      = (const int*)d_in[14];
    float* out = (float*)d_out;

    float* ws   = (float*)d_ws;
    float* enc  = ws;                         // 32768*200
    float* Mar  = ws + 6553600;               // 32767*200
    float* P    = ws + 13107000;              // 32767*512 (row 0 unused)
    float* WAB  = ws + 29883704;              // 48*200
    float* WBC  = WAB + 9600;                 // 48*200
    float* msAB = WBC + 9600;                 // 48
    float* msBC = msAB + 48;                  // 48
    float* TM = P;                            // 32767*48 (overlays dead P)
    float* TE = P + 1572816;                  // 32768*48

    gemm_bt<<<dim3(512, 4, 1), 256, 0, stream>>>(enc_cls, 768, W_proj, 768, b_proj,
                                                 enc, 200, N_EDUS, 200, 768);
    gemm_bt<<<dim3(512, 8, 1), 256, 0, stream>>>(enc + 200, 200, W_tree + 100, 200, b_tree,
                                                 P + 512, 512, KMAX, 500, 100);
    prep_kernel<<<1, 256, 0, stream>>>(W_act, W_lab, W_dir, miss, WAB, WBC, msAB, msBC, out);
    chain_kernel<<<1, 512, 0, stream>>>(enc, W_tree, P, Mar);
    gemm_bt<<<dim3(512, 1, 1), 256, 0, stream>>>(Mar, 200, WAB, 200, nullptr,
                                                 TM, 48, KMAX + 1, 48, 200);
    gemm_bt<<<dim3(512, 1, 1), 256, 0, stream>>>(enc, 200, WBC, 200, nullptr,
                                                 TE, 48, N_EDUS, 48, 200);
    loss_kernel<<<dim3(256, 1, 1), 256, 0, stream>>>(TM, TE, msAB, msBC,
                                                     b_act, b_lab, b_dir, ga, gl, gd, out);
}

// Round 3
// 32088.129 us; speedup vs baseline: 1.2986x; 1.1294x over previous
//
#include <hip/hip_runtime.h>
#include <cstdint>

#define HID 200
#define HALF 100
#define N_EDUS 32768
#define N_STEPS (2*N_EDUS - 1)   // 65535
#define KMAX 32766               // chain computes M_1..M_32766 (M_0 = enc[0])

// ---------------- generic tiled GEMM: C[m][n] = bias[n] + sum_k A[m][k]*B[n][k] ----------------
__global__ __launch_bounds__(256) void gemm_bt(const float* __restrict__ A, int lda,
    const float* __restrict__ B, int ldb, const float* __restrict__ bias,
    float* __restrict__ C, int ldc, int M, int N, int K)
{
    __shared__ float As[32][68];
    __shared__ float Bs[32][68];
    const int tid = threadIdx.x;
    const int tx = tid & 15, ty = tid >> 4;
    const int m0 = blockIdx.x * 64, n0 = blockIdx.y * 64;
    float acc[4][4] = {};
    for (int kc = 0; kc < K; kc += 32) {
        const int kk = tid & 31, r0 = tid >> 5;
        #pragma unroll
        for (int p = 0; p < 8; ++p) {
            const int mm = r0 + p * 8;
            const int m = m0 + mm, n = n0 + mm, kg = kc + kk;
            As[kk][mm] = (m < M && kg < K) ? A[(size_t)m * lda + kg] : 0.f;
            Bs[kk][mm] = (n < N && kg < K) ? B[(size_t)n * ldb + kg] : 0.f;
        }
        __syncthreads();
        #pragma unroll
        for (int kk2 = 0; kk2 < 32; ++kk2) {
            const float4 a = *(const float4*)&As[kk2][tx * 4];
            const float4 b = *(const float4*)&Bs[kk2][ty * 4];
            const float av[4] = {a.x, a.y, a.z, a.w};
            const float bv[4] = {b.x, b.y, b.z, b.w};
            #pragma unroll
            for (int r = 0; r < 4; ++r)
                #pragma unroll
                for (int c = 0; c < 4; ++c)
                    acc[r][c] += av[r] * bv[c];
        }
        __syncthreads();
    }
    #pragma unroll
    for (int r = 0; r < 4; ++r) {
        const int m = m0 + tx * 4 + r;
        if (m >= M) continue;
        #pragma unroll
        for (int c = 0; c < 4; ++c) {
            const int n = n0 + ty * 4 + c;
            if (n < N) C[(size_t)m * ldc + n] = acc[r][c] + (bias ? bias[n] : 0.f);
        }
    }
}

// ---------------- prep ----------------
__global__ void prep_kernel(const float* __restrict__ W_act, const float* __restrict__ W_lab,
    const float* __restrict__ W_dir, const float* __restrict__ miss,
    float* __restrict__ WAB, float* __restrict__ WBC,
    float* __restrict__ msAB, float* __restrict__ msBC, float* __restrict__ out)
{
    const int tid = threadIdx.x;
    if (tid == 0) out[0] = 0.f;
    for (int i = tid; i < 48 * 200; i += 256) {
        const int r = i / 200, c = i % 200;
        const int rr = r % 24;
        const float* src = (rr < 2) ? (W_act + rr * 600)
                         : (rr < 21) ? (W_lab + (rr - 2) * 600)
                                     : (W_dir + (rr - 21) * 600);
        WAB[i] = src[c + (r < 24 ? 0 : 200)];
        WBC[i] = src[c + (r < 24 ? 200 : 400)];
    }
    __syncthreads();
    if (tid < 48) {
        float sA = 0.f, sB = 0.f;
        for (int c = 0; c < 200; ++c) {
            sA += WAB[tid * 200 + c] * miss[c];
            sB += WBC[tid * 200 + c] * miss[c];
        }
        msAB[tid] = sA;
        msBC[tid] = sB;
    }
}

// ---------------- sequential treelstm chain ----------------
__device__ __forceinline__ float sigf(float x) {
    return __builtin_amdgcn_rcpf(1.f + __expf(-x));
}
__device__ __forceinline__ float tanhf_(float x) {
    return 1.f - 2.f * __builtin_amdgcn_rcpf(1.f + __expf(2.f * x));
}

// raw barrier: drain LDS only, leave global prefetch loads (vmcnt) in flight
#define BAR() asm volatile("s_waitcnt lgkmcnt(0)\n\ts_barrier" ::: "memory")
// pin a value into a VGPR: opaque redefinition — compiler can't rematerialize
// or sink the producing load into the loop; forces true register residency
#define KEEP(x) asm volatile("" : "+v"(x))

// 512 threads: T -> (d = T>>2 in [0,128), q = T&3). Active d<100.
// lane (d,q): W_tree[:,0:100] rows {d,d+100,..,d+400} over j-chunk [25q,25q+25) in 125 VGPRs.
// gate epilogue distributed over quad: q0=sig(i)*tanh(u), q1=sig(f1)*c1, q2=sig(f2)*c2, q3=sig(o).
// P row (enc-half of gates incl. b_tree) + c2 prefetched 2 steps ahead, per-quad-lane.
__global__ __launch_bounds__(512, 2) void chain_kernel(const float* __restrict__ enc,
    const float* __restrict__ W_tree, const float* __restrict__ P, float* __restrict__ M)
{
    const int T = threadIdx.x;
    const int d = T >> 2, q = T & 3;
    const bool act = (d < 100);
    __shared__ float hbuf[2][4 * 36];

    if (T < 200) M[T] = enc[T];   // M_0 = enc[0]

    const int dd = act ? d : 0;   // clamp so all lanes load valid W (uniform code, W fully defined)
    float W[5][25];
    #pragma unroll
    for (int g = 0; g < 5; ++g)
        #pragma unroll
        for (int j = 0; j < 25; ++j)
            W[g][j] = W_tree[(size_t)(g * 100 + dd) * 200 + q * 25 + j];
    // pin all 125 into VGPRs — prevents the R1 failure mode (loads sunk into loop, L2 re-read)
    #pragma unroll
    for (int g = 0; g < 5; ++g)
        #pragma unroll
        for (int j = 0; j < 25; ++j)
            KEEP(W[g][j]);

    const int hslot = (d / 25) * 36 + (d % 25);
    const int goA = q * 100 + d;      // this lane's primary gate slot in a P row
    const int goB = 400 + d;          // u-gate slot (q0 only)

    float c_reg = 0.f;                                // cell state, lives at q1
    float pa_c = 0, pb_c = 0, c2_c = 0;               // step k
    float pa_1 = 0, pb_1 = 0, c2_1 = 0;               // step k+1
    if (act) {
        if (q == 1) c_reg = enc[100 + d];
        if (q == 0) hbuf[0][hslot] = enc[d];
        pa_c = P[(size_t)1 * 512 + goA];
        if (q == 0) pb_c = P[(size_t)1 * 512 + goB];
        if (q == 2) c2_c = enc[(size_t)1 * 200 + 100 + d];
        pa_1 = P[(size_t)2 * 512 + goA];
        if (q == 0) pb_1 = P[(size_t)2 * 512 + goB];
        if (q == 2) c2_1 = enc[(size_t)2 * 200 + 100 + d];
    }
    BAR();

    int cur = 0;
    for (int k = 1; k <= KMAX; ++k) {
        // prefetch step k+2 (2-step distance covers latency across raw barriers)
        float pa_2 = 0.f, pb_2 = 0.f, c2_2 = 0.f;
        if (act && k + 2 <= KMAX) {
            pa_2 = P[(size_t)(k + 2) * 512 + goA];
            if (q == 0) pb_2 = P[(size_t)(k + 2) * 512 + goB];
            if (q == 2) c2_2 = enc[(size_t)(k + 2) * 200 + 100 + d];
        }
        float s[5] = {0.f, 0.f, 0.f, 0.f, 0.f};
        {
            float hr[25];
            const float* hb = &hbuf[cur][q * 36];
            #pragma unroll
            for (int jj = 0; jj < 6; ++jj) {
                const float4 h4 = *(const float4*)(hb + jj * 4);
                hr[jj * 4 + 0] = h4.x; hr[jj * 4 + 1] = h4.y;
                hr[jj * 4 + 2] = h4.z; hr[jj * 4 + 3] = h4.w;
            }
            hr[24] = hb[24];
            #pragma unroll
            for (int g = 0; g < 5; ++g) {
                float a = 0.f;
                #pragma unroll
                for (int j = 0; j < 25; ++j) a = fmaf(W[g][j], hr[j], a);
                s[g] = a;
            }
        }
        #pragma unroll
        for (int g = 0; g < 5; ++g) {   // quad butterfly: all 4 quad lanes get full sums
            s[g] += __shfl_xor(s[g], 1, 64);
            s[g] += __shfl_xor(s[g], 2, 64);
        }
        if (act) {
            const float prim = (q == 0) ? s[0] : (q == 1) ? s[1] : (q == 2) ? s[2] : s[3];
            const float sg = sigf(prim + pa_c);            // at q3 this is sig(o)
            const float mult = (q == 0) ? tanhf_(s[4] + pb_c)
                             : (q == 1) ? c_reg
                             : (q == 2) ? c2_c : 0.f;
            float a = sg * mult;
            a += __shfl_xor(a, 1, 64);
            a += __shfl_xor(a, 2, 64);                     // a == new cell c, all quad lanes
            if (q == 3) {
                const float h = sg * tanhf_(a);
                hbuf[cur ^ 1][hslot] = h;
                M[(size_t)k * 200 + d] = h;
            } else if (q == 1) {
                c_reg = a;
                M[(size_t)k * 200 + 100 + d] = a;
            }
            pa_c = pa_1; pb_c = pb_1; c2_c = c2_1;
            pa_1 = pa_2; pb_1 = pb_2; c2_1 = c2_2;
        }
        cur ^= 1;
        BAR();
    }
}

// ---------------- per-step CE losses + reduction ----------------
__global__ __launch_bounds__(256) void loss_kernel(const float* __restrict__ TM,
    const float* __restrict__ TE, const float* __restrict__ msAB, const float* __restrict__ msBC,
    const float* __restrict__ b_act, const float* __restrict__ b_lab, const float* __restrict__ b_dir,
    const int* __restrict__ ga, const int* __restrict__ gl, const int* __restrict__ gd,
    float* __restrict__ out)
{
    const int t = blockIdx.x * 256 + threadIdx.x;
    float loss = 0.f;
    if (t < N_STEPS) {
        const float *v1, *v0, *vb;
        if (t == 0)      { v1 = msAB; v0 = msAB + 24; vb = TE + 24; }
        else if (t == 1) { v1 = msAB; v0 = TE;        vb = TE + 48 + 24; }
        else if ((t & 1) == 0) {
            const int k = t >> 1;
            v1 = TM + (size_t)(k - 1) * 48;
            v0 = TE + (size_t)k * 48;
            vb = (k < N_EDUS - 1) ? (TE + (size_t)(k + 1) * 48 + 24) : (msBC + 24);
        } else {
            const int k = t >> 1;
            v1 = msAB;
            v0 = TM + (size_t)k * 48 + 24;
            vb = TE + (size_t)(k + 1) * 48 + 24;
        }
        float l[24];
        #pragma unroll
        for (int j = 0; j < 24; ++j) l[j] = v1[j] + v0[j] + vb[j];
        l[0] += b_act[0]; l[1] += b_act[1];
        #pragma unroll
        for (int j = 0; j < 19; ++j) l[2 + j] += b_lab[j];
        #pragma unroll
        for (int j = 0; j < 3; ++j) l[21 + j] += b_dir[j];
        const int ya = ga[t], yl = gl[t], yd = gd[t];
        {
            const float m = fmaxf(l[0], l[1]);
            const float sum = __expf(l[0] - m) + __expf(l[1] - m);
            loss += m + __logf(sum) - (ya == 0 ? l[0] : l[1]);
        }
        {
            float m = l[2];
            #pragma unroll
            for (int j = 1; j < 19; ++j) m = fmaxf(m, l[2 + j]);
            float sum = 0.f, ly = 0.f;
            #pragma unroll
            for (int j = 0; j < 19; ++j) {
                sum += __expf(l[2 + j] - m);
                if (j == yl) ly = l[2 + j];
            }
            loss += m + __logf(sum) - ly;
        }
        {
            const float m = fmaxf(fmaxf(l[21], l[22]), l[23]);
            const float sum = __expf(l[21] - m) + __expf(l[22] - m) + __expf(l[23] - m);
            const float ly = (yd == 0) ? l[21] : (yd == 1 ? l[22] : l[23]);
            loss += m + __logf(sum) - ly;
        }
    }
    #pragma unroll
    for (int off = 32; off > 0; off >>= 1) loss += __shfl_down(loss, off, 64);
    __shared__ float wsum[4];
    const int lane = threadIdx.x & 63, wv = threadIdx.x >> 6;
    if (lane == 0) wsum[wv] = loss;
    __syncthreads();
    if (threadIdx.x == 0) atomicAdd(out, wsum[0] + wsum[1] + wsum[2] + wsum[3]);
}

// ---------------- launch ----------------
extern "C" void kernel_launch(void* const* d_in, const int* in_sizes, int n_in,
                              void* d_out, int out_size, void* d_ws, size_t ws_size,
                              hipStream_t stream) {
    const float* enc_cls = (const float*)d_in[0];
    const float* W_proj  = (const float*)d_in[1];
    const float* b_proj  = (const float*)d_in[2];
    const float* miss    = (const float*)d_in[3];
    const float* W_act   = (const float*)d_in[4];
    const float* b_act   = (const float*)d_in[5];
    const float* W_lab   = (const float*)d_in[6];
    const float* b_lab   = (const float*)d_in[7];
    const float* W_dir   = (const float*)d_in[8];
    const float* b_dir   = (const float*)d_in[9];
    const float* W_tree  = (const float*)d_in[10];
    const float* b_tree  = (const float*)d_in[11];
    const int*   ga      = (const int*)d_in[12];
    const int*   gl      = (const int*)d_in[13];
    const int*   gd      = (const int*)d_in[14];
    float* out = (float*)d_out;

    float* ws   = (float*)d_ws;
    float* enc  = ws;                         // 32768*200
    float* Mar  = ws + 6553600;               // 32767*200
    float* P    = ws + 13107000;              // 32767*512 (row 0 unused)
    float* WAB  = ws + 29883704;              // 48*200
    float* WBC  = WAB + 9600;                 // 48*200
    float* msAB = WBC + 9600;                 // 48
    float* msBC = msAB + 48;                  // 48
    float* TM = P;                            // 32767*48 (overlays dead P)
    float* TE = P + 1572816;                  // 32768*48

    gemm_bt<<<dim3(512, 4, 1), 256, 0, stream>>>(enc_cls, 768, W_proj, 768, b_proj,
                                                 enc, 200, N_EDUS, 200, 768);
    gemm_bt<<<dim3(512, 8, 1), 256, 0, stream>>>(enc + 200, 200, W_tree + 100, 200, b_tree,
                                                 P + 512, 512, KMAX, 500, 100);
    prep_kernel<<<1, 256, 0, stream>>>(W_act, W_lab, W_dir, miss, WAB, WBC, msAB, msBC, out);
    chain_kernel<<<1, 512, 0, stream>>>(enc, W_tree, P, Mar);
    gemm_bt<<<dim3(512, 1, 1), 256, 0, stream>>>(Mar, 200, WAB, 200, nullptr,
                                                 TM, 48, KMAX + 1, 48, 200);
    gemm_bt<<<dim3(512, 1, 1), 256, 0, stream>>>(enc, 200, WBC, 200, nullptr,
                                                 TE, 48, N_EDUS, 48, 200);
    loss_kernel<<<dim3(256, 1, 1), 256, 0, stream>>>(TM, TE, msAB, msBC,
                                                     b_act, b_lab, b_dir, ga, gl, gd, out);
}

// Round 4
// 32040.921 us; speedup vs baseline: 1.3005x; 1.0015x over previous
//
#include <hip/hip_runtime.h>
#include <cstdint>

#define HID 200
#define HALF 100
#define N_EDUS 32768
#define N_STEPS (2*N_EDUS - 1)   // 65535
#define KMAX 32766               // chain computes M_1..M_32766 (M_0 = enc[0])

// ---------------- generic tiled GEMM: C[m][n] = bias[n] + sum_k A[m][k]*B[n][k] ----------------
__global__ __launch_bounds__(256) void gemm_bt(const float* __restrict__ A, int lda,
    const float* __restrict__ B, int ldb, const float* __restrict__ bias,
    float* __restrict__ C, int ldc, int M, int N, int K)
{
    __shared__ float As[32][68];
    __shared__ float Bs[32][68];
    const int tid = threadIdx.x;
    const int tx = tid & 15, ty = tid >> 4;
    const int m0 = blockIdx.x * 64, n0 = blockIdx.y * 64;
    float acc[4][4] = {};
    for (int kc = 0; kc < K; kc += 32) {
        const int kk = tid & 31, r0 = tid >> 5;
        #pragma unroll
        for (int p = 0; p < 8; ++p) {
            const int mm = r0 + p * 8;
            const int m = m0 + mm, n = n0 + mm, kg = kc + kk;
            As[kk][mm] = (m < M && kg < K) ? A[(size_t)m * lda + kg] : 0.f;
            Bs[kk][mm] = (n < N && kg < K) ? B[(size_t)n * ldb + kg] : 0.f;
        }
        __syncthreads();
        #pragma unroll
        for (int kk2 = 0; kk2 < 32; ++kk2) {
            const float4 a = *(const float4*)&As[kk2][tx * 4];
            const float4 b = *(const float4*)&Bs[kk2][ty * 4];
            const float av[4] = {a.x, a.y, a.z, a.w};
            const float bv[4] = {b.x, b.y, b.z, b.w};
            #pragma unroll
            for (int r = 0; r < 4; ++r)
                #pragma unroll
                for (int c = 0; c < 4; ++c)
                    acc[r][c] += av[r] * bv[c];
        }
        __syncthreads();
    }
    #pragma unroll
    for (int r = 0; r < 4; ++r) {
        const int m = m0 + tx * 4 + r;
        if (m >= M) continue;
        #pragma unroll
        for (int c = 0; c < 4; ++c) {
            const int n = n0 + ty * 4 + c;
            if (n < N) C[(size_t)m * ldc + n] = acc[r][c] + (bias ? bias[n] : 0.f);
        }
    }
}

// ---------------- prep ----------------
__global__ void prep_kernel(const float* __restrict__ W_act, const float* __restrict__ W_lab,
    const float* __restrict__ W_dir, const float* __restrict__ miss,
    float* __restrict__ WAB, float* __restrict__ WBC,
    float* __restrict__ msAB, float* __restrict__ msBC, float* __restrict__ out)
{
    const int tid = threadIdx.x;
    if (tid == 0) out[0] = 0.f;
    for (int i = tid; i < 48 * 200; i += 256) {
        const int r = i / 200, c = i % 200;
        const int rr = r % 24;
        const float* src = (rr < 2) ? (W_act + rr * 600)
                         : (rr < 21) ? (W_lab + (rr - 2) * 600)
                                     : (W_dir + (rr - 21) * 600);
        WAB[i] = src[c + (r < 24 ? 0 : 200)];
        WBC[i] = src[c + (r < 24 ? 200 : 400)];
    }
    __syncthreads();
    if (tid < 48) {
        float sA = 0.f, sB = 0.f;
        for (int c = 0; c < 200; ++c) {
            sA += WAB[tid * 200 + c] * miss[c];
            sB += WBC[tid * 200 + c] * miss[c];
        }
        msAB[tid] = sA;
        msBC[tid] = sB;
    }
}

// ---------------- sequential treelstm chain ----------------
__device__ __forceinline__ float sigf(float x) {
    return __builtin_amdgcn_rcpf(1.f + __expf(-x));
}
__device__ __forceinline__ float tanhf_(float x) {
    return 1.f - 2.f * __builtin_amdgcn_rcpf(1.f + __expf(2.f * x));
}

// raw barrier: drain LDS only, leave global prefetch loads (vmcnt) in flight
#define BAR() asm volatile("s_waitcnt lgkmcnt(0)\n\ts_barrier" ::: "memory")
// pin a value into a VGPR: opaque redefinition — compiler can't rematerialize
// or sink the producing load into the loop
#define KEEP(x) asm volatile("" : "+v"(x))

// 512 threads: T -> (d = T>>2 in [0,128), q = T&3). Active d<100.
// lane (d,q): W_tree[:,0:100] rows {d,d+100,..,d+400} over j-chunk [25q,25q+25) in 125 VGPRs.
// amdgpu_waves_per_eu(2,2): clamp occupancy target to EXACTLY 2 waves/EU so the
// register allocator budgets 256 VGPRs/wave and stops spilling W to scratch
// (R2/R3 failure: launch_bounds min-occupancy still let the scheduler target 8
// waves/EU and spill all 125 W values -> 256KB/step L2 scratch traffic).
__attribute__((amdgpu_waves_per_eu(2, 2)))
__global__ __launch_bounds__(512) void chain_kernel(const float* __restrict__ enc,
    const float* __restrict__ W_tree, const float* __restrict__ P, float* __restrict__ M)
{
    const int T = threadIdx.x;
    const int d = T >> 2, q = T & 3;
    const bool act = (d < 100);
    __shared__ float hbuf[2][4 * 36];

    if (T < 200) M[T] = enc[T];   // M_0 = enc[0]

    const int dd = act ? d : 0;   // clamp so all lanes load valid W (uniform code, W fully defined)
    float W[5][25];
    #pragma unroll
    for (int g = 0; g < 5; ++g)
        #pragma unroll
        for (int j = 0; j < 25; ++j)
            W[g][j] = W_tree[(size_t)(g * 100 + dd) * 200 + q * 25 + j];
    #pragma unroll
    for (int g = 0; g < 5; ++g)
        #pragma unroll
        for (int j = 0; j < 25; ++j)
            KEEP(W[g][j]);

    const int hslot = (d / 25) * 36 + (d % 25);
    const int goA = q * 100 + d;      // this lane's primary gate slot in a P row
    const int goB = 400 + d;          // u-gate slot (q0 only)

    float c_reg = 0.f;                                // cell state, lives at q1
    float pa_c = 0, pb_c = 0, c2_c = 0;               // step k
    float pa_1 = 0, pb_1 = 0, c2_1 = 0;               // step k+1
    if (act) {
        if (q == 1) c_reg = enc[100 + d];
        if (q == 0) hbuf[0][hslot] = enc[d];
        pa_c = P[(size_t)1 * 512 + goA];
        if (q == 0) pb_c = P[(size_t)1 * 512 + goB];
        if (q == 2) c2_c = enc[(size_t)1 * 200 + 100 + d];
        pa_1 = P[(size_t)2 * 512 + goA];
        if (q == 0) pb_1 = P[(size_t)2 * 512 + goB];
        if (q == 2) c2_1 = enc[(size_t)2 * 200 + 100 + d];
    }
    BAR();

    int cur = 0;
    for (int k = 1; k <= KMAX; ++k) {
        // prefetch step k+2 (2-step distance covers latency across raw barriers)
        float pa_2 = 0.f, pb_2 = 0.f, c2_2 = 0.f;
        if (act && k + 2 <= KMAX) {
            pa_2 = P[(size_t)(k + 2) * 512 + goA];
            if (q == 0) pb_2 = P[(size_t)(k + 2) * 512 + goB];
            if (q == 2) c2_2 = enc[(size_t)(k + 2) * 200 + 100 + d];
        }
        float s[5] = {0.f, 0.f, 0.f, 0.f, 0.f};
        {
            float hr[25];
            const float* hb = &hbuf[cur][q * 36];
            #pragma unroll
            for (int jj = 0; jj < 6; ++jj) {
                const float4 h4 = *(const float4*)(hb + jj * 4);
                hr[jj * 4 + 0] = h4.x; hr[jj * 4 + 1] = h4.y;
                hr[jj * 4 + 2] = h4.z; hr[jj * 4 + 3] = h4.w;
            }
            hr[24] = hb[24];
            #pragma unroll
            for (int g = 0; g < 5; ++g) {
                float a = 0.f;
                #pragma unroll
                for (int j = 0; j < 25; ++j) a = fmaf(W[g][j], hr[j], a);
                s[g] = a;
            }
        }
        #pragma unroll
        for (int g = 0; g < 5; ++g) {   // quad butterfly: all 4 quad lanes get full sums
            s[g] += __shfl_xor(s[g], 1, 64);
            s[g] += __shfl_xor(s[g], 2, 64);
        }
        if (act) {
            const float prim = (q == 0) ? s[0] : (q == 1) ? s[1] : (q == 2) ? s[2] : s[3];
            const float sg = sigf(prim + pa_c);            // at q3 this is sig(o)
            const float mult = (q == 0) ? tanhf_(s[4] + pb_c)
                             : (q == 1) ? c_reg
                             : (q == 2) ? c2_c : 0.f;
            float a = sg * mult;
            a += __shfl_xor(a, 1, 64);
            a += __shfl_xor(a, 2, 64);                     // a == new cell c, all quad lanes
            if (q == 3) {
                const float h = sg * tanhf_(a);
                hbuf[cur ^ 1][hslot] = h;
                M[(size_t)k * 200 + d] = h;
            } else if (q == 1) {
                c_reg = a;
                M[(size_t)k * 200 + 100 + d] = a;
            }
            pa_c = pa_1; pb_c = pb_1; c2_c = c2_1;
            pa_1 = pa_2; pb_1 = pb_2; c2_1 = c2_2;
        }
        cur ^= 1;
        BAR();
    }
}

// ---------------- per-step CE losses + reduction ----------------
__global__ __launch_bounds__(256) void loss_kernel(const float* __restrict__ TM,
    const float* __restrict__ TE, const float* __restrict__ msAB, const float* __restrict__ msBC,
    const float* __restrict__ b_act, const float* __restrict__ b_lab, const float* __restrict__ b_dir,
    const int* __restrict__ ga, const int* __restrict__ gl, const int* __restrict__ gd,
    float* __restrict__ out)
{
    const int t = blockIdx.x * 256 + threadIdx.x;
    float loss = 0.f;
    if (t < N_STEPS) {
        const float *v1, *v0, *vb;
        if (t == 0)      { v1 = msAB; v0 = msAB + 24; vb = TE + 24; }
        else if (t == 1) { v1 = msAB; v0 = TE;        vb = TE + 48 + 24; }
        else if ((t & 1) == 0) {
            const int k = t >> 1;
            v1 = TM + (size_t)(k - 1) * 48;
            v0 = TE + (size_t)k * 48;
            vb = (k < N_EDUS - 1) ? (TE + (size_t)(k + 1) * 48 + 24) : (msBC + 24);
        } else {
            const int k = t >> 1;
            v1 = msAB;
            v0 = TM + (size_t)k * 48 + 24;
            vb = TE + (size_t)(k + 1) * 48 + 24;
        }
        float l[24];
        #pragma unroll
        for (int j = 0; j < 24; ++j) l[j] = v1[j] + v0[j] + vb[j];
        l[0] += b_act[0]; l[1] += b_act[1];
        #pragma unroll
        for (int j = 0; j < 19; ++j) l[2 + j] += b_lab[j];
        #pragma unroll
        for (int j = 0; j < 3; ++j) l[21 + j] += b_dir[j];
        const int ya = ga[t], yl = gl[t], yd = gd[t];
        {
            const float m = fmaxf(l[0], l[1]);
            const float sum = __expf(l[0] - m) + __expf(l[1] - m);
            loss += m + __logf(sum) - (ya == 0 ? l[0] : l[1]);
        }
        {
            float m = l[2];
            #pragma unroll
            for (int j = 1; j < 19; ++j) m = fmaxf(m, l[2 + j]);
            float sum = 0.f, ly = 0.f;
            #pragma unroll
            for (int j = 0; j < 19; ++j) {
                sum += __expf(l[2 + j] - m);
                if (j == yl) ly = l[2 + j];
            }
            loss += m + __logf(sum) - ly;
        }
        {
            const float m = fmaxf(fmaxf(l[21], l[22]), l[23]);
            const float sum = __expf(l[21] - m) + __expf(l[22] - m) + __expf(l[23] - m);
            const float ly = (yd == 0) ? l[21] : (yd == 1 ? l[22] : l[23]);
            loss += m + __logf(sum) - ly;
        }
    }
    #pragma unroll
    for (int off = 32; off > 0; off >>= 1) loss += __shfl_down(loss, off, 64);
    __shared__ float wsum[4];
    const int lane = threadIdx.x & 63, wv = threadIdx.x >> 6;
    if (lane == 0) wsum[wv] = loss;
    __syncthreads();
    if (threadIdx.x == 0) atomicAdd(out, wsum[0] + wsum[1] + wsum[2] + wsum[3]);
}

// ---------------- launch ----------------
extern "C" void kernel_launch(void* const* d_in, const int* in_sizes, int n_in,
                              void* d_out, int out_size, void* d_ws, size_t ws_size,
                              hipStream_t stream) {
    const float* enc_cls = (const float*)d_in[0];
    const float* W_proj  = (const float*)d_in[1];
    const float* b_proj  = (const float*)d_in[2];
    const float* miss    = (const float*)d_in[3];
    const float* W_act   = (const float*)d_in[4];
    const float* b_act   = (const float*)d_in[5];
    const float* W_lab   = (const float*)d_in[6];
    const float* b_lab   = (const float*)d_in[7];
    const float* W_dir   = (const float*)d_in[8];
    const float* b_dir   = (const float*)d_in[9];
    const float* W_tree  = (const float*)d_in[10];
    const float* b_tree  = (const float*)d_in[11];
    const int*   ga      = (const int*)d_in[12];
    const int*   gl      = (const int*)d_in[13];
    const int*   gd      = (const int*)d_in[14];
    float* out = (float*)d_out;

    float* ws   = (float*)d_ws;
    float* enc  = ws;                         // 32768*200
    float* Mar  = ws + 6553600;               // 32767*200
    float* P    = ws + 13107000;              // 32767*512 (row 0 unused)
    float* WAB  = ws + 29883704;              // 48*200
    float* WBC  = WAB + 9600;                 // 48*200
    float* msAB = WBC + 9600;                 // 48
    float* msBC = msAB + 48;                  // 48
    float* TM = P;                            // 32767*48 (overlays dead P)
    float* TE = P + 1572816;                  // 32768*48

    gemm_bt<<<dim3(512, 4, 1), 256, 0, stream>>>(enc_cls, 768, W_proj, 768, b_proj,
                                                 enc, 200, N_EDUS, 200, 768);
    gemm_bt<<<dim3(512, 8, 1), 256, 0, stream>>>(enc + 200, 200, W_tree + 100, 200, b_tree,
                                                 P + 512, 512, KMAX, 500, 100);
    prep_kernel<<<1, 256, 0, stream>>>(W_act, W_lab, W_dir, miss, WAB, WBC, msAB, msBC, out);
    chain_kernel<<<1, 512, 0, stream>>>(enc, W_tree, P, Mar);
    gemm_bt<<<dim3(512, 1, 1), 256, 0, stream>>>(Mar, 200, WAB, 200, nullptr,
                                                 TM, 48, KMAX + 1, 48, 200);
    gemm_bt<<<dim3(512, 1, 1), 256, 0, stream>>>(enc, 200, WBC, 200, nullptr,
                                                 TE, 48, N_EDUS, 48, 200);
    loss_kernel<<<dim3(256, 1, 1), 256, 0, stream>>>(TM, TE, msAB, msBC,
                                                     b_act, b_lab, b_dir, ga, gl, gd, out);
}